// Round 4
// baseline (300.849 us; speedup 1.0000x reference)
//
#include <hip/hip_runtime.h>
#include <stdint.h>

// FourierPeriodNet: out[m][c] = sum_f sin(2pi t[m] f[f]) As[c][f] + cos(...) Ac[c][f]
// M = 262144, F = 128, C = 256.
// Round 7: de-convoy. Round-3 A/B showed nt stores caused the round-2
// regression (reverted; lgkmcnt-only barrier neutral -> kept). No pipe is near
// saturation at 2 blocks/CU -> convoy/latency-bound. This round: 4 blocks/CU.
//   - MT=32 rows/tile, block covers 128 channels (C-split x2; trans computed
//     twice per row -- cheap, trans pipe has ~10x headroom).
//   - LDS double buffer 2x16.9KB = 33.8KB -> 4 blocks/CU fit (135KB < 160KB).
//   - b[8][2] (64 VGPR) + acc[2][2] (16) -> ~120 VGPR, launch_bounds(256,4)
//     -> 16 waves/CU, staggered blocks fill barrier/latency gaps, smoother
//     HBM write stream.
//   - Swapped MFMA operands: mfma(amp_frag, feat_frag, acc). Register contents
//     are identical under the swap (B[k][n]=amp[n][k] content == A[row][k]
//     content with row=channel; feat reads already match the B layout).
//     D then has channel=row=(lane>>4)*4+reg, m=col=lane&15 -> each lane holds
//     4 CONSECUTIVE channels -> epilogue is 4 dwordx4 stores/thread/tile
//     (was 16 scattered dword stores).

typedef __bf16 bf16x8 __attribute__((ext_vector_type(8)));
typedef float  floatx4 __attribute__((ext_vector_type(4)));

#define MT    32          // M rows per tile
#define F_    128         // frequencies
#define C_    256         // total channels
#define CB    128         // channels per block
#define LSTR  264         // LDS row stride in bf16 elems: 256 + 8 pad
#define TPB   8           // tiles per block

// Orders LDS only: drain this wave's DS ops, then raw s_barrier. Global stores
// stay outstanding (write-only output, no in-kernel reader).
#define LDS_BARRIER() asm volatile("s_waitcnt lgkmcnt(0)\n\ts_barrier" ::: "memory")

__global__ __launch_bounds__(256, 4)
void fourier_fused(const float* __restrict__ t,
                   const float* __restrict__ freqs,
                   const float* __restrict__ amp_sin,
                   const float* __restrict__ amp_cos,
                   float* __restrict__ out)
{
    __shared__ __align__(16) __bf16 Af[2][MT * LSTR];   // 2 x 16896 B

    const int tid  = threadIdx.x;
    const int wave = tid >> 6;       // 0..3 -> 32-col slice of this block's 128
    const int lane = tid & 63;
    const int l15  = lane & 15;
    const int quad = lane >> 4;      // 0..3

    const int cblk = blockIdx.x & 1;         // which 128-channel half
    const int mblk = blockIdx.x >> 1;
    const int n0   = cblk * CB + wave * 32;

    const int fgrp = tid & 15;       // which octet of 8 freqs (phase 1)
    const int rsub = tid >> 4;       // 0..15 (row-within-16 in phase 1)

    const int tile0 = mblk * TPB;

    // ---- t for tile 0 (in flight during freq/B setup) ----
    float tv[2];
    tv[0] = t[tile0 * MT + rsub];
    tv[1] = t[tile0 * MT + 16 + rsub];

    // ---- freqs for phase 1 ----
    const float4 f0v = *(const float4*)(freqs + fgrp * 8);
    const float4 f1v = *(const float4*)(freqs + fgrp * 8 + 4);
    const float fr[8] = {f0v.x, f0v.y, f0v.z, f0v.w, f1v.x, f1v.y, f1v.z, f1v.w};

    // ---- amp fragments (A-operand of swapped MFMA), held in VGPRs.
    // Lane (quad,l15) holds amp[n0 + ni*16 + l15][(ks&3)*32 + quad*8 + j],
    // ks<4 -> amp_sin (k=0..127), ks>=4 -> amp_cos (k=128..255).
    bf16x8 b[8][2];
    #pragma unroll
    for (int ks = 0; ks < 8; ++ks) {
        const float* __restrict__ amp = (ks < 4) ? amp_sin : amp_cos;
        const int f0 = (ks & 3) * 32 + quad * 8;
        #pragma unroll
        for (int ni = 0; ni < 2; ++ni) {
            const float* p = amp + (n0 + ni * 16 + l15) * F_ + f0;
            const float4 b0 = *(const float4*)(p);
            const float4 b1 = *(const float4*)(p + 4);
            b[ks][ni][0] = (__bf16)b0.x; b[ks][ni][1] = (__bf16)b0.y;
            b[ks][ni][2] = (__bf16)b0.z; b[ks][ni][3] = (__bf16)b0.w;
            b[ks][ni][4] = (__bf16)b1.x; b[ks][ni][5] = (__bf16)b1.y;
            b[ks][ni][6] = (__bf16)b1.z; b[ks][ni][7] = (__bf16)b1.w;
        }
    }

    #pragma unroll 2
    for (int it = 0; it < TPB; ++it) {
        const int m0 = (tile0 + it) * MT;
        __bf16* __restrict__ A = Af[it & 1];

        // ---- prefetch next tile's t ----
        float tvn[2];
        {
            const int mb = (it + 1 < TPB) ? (m0 + MT) : tile0 * MT;
            tvn[0] = t[mb + rsub];
            tvn[1] = t[mb + 16 + rsub];
        }

        // ---- phase 1: sin/cos features -> LDS (bf16, [m][k] rows) ----
        #pragma unroll
        for (int pass = 0; pass < 2; ++pass) {
            const int ml = pass * 16 + rsub;
            const float tval = tv[pass];
            bf16x8 sv, cv;
            #pragma unroll
            for (int j = 0; j < 8; ++j) {
                // sin(2*pi*x) = v_sin(fract(x)): HW sin/cos take REVOLUTIONS
                const float r = __builtin_amdgcn_fractf(tval * fr[j]);
                sv[j] = (__bf16)__builtin_amdgcn_sinf(r);
                cv[j] = (__bf16)__builtin_amdgcn_cosf(r);
            }
            *(bf16x8*)&A[ml * LSTR + fgrp * 8]      = sv;   // k = 0..127  : sin
            *(bf16x8*)&A[ml * LSTR + F_ + fgrp * 8] = cv;   // k = 128..255: cos
        }
        LDS_BARRIER();
        // Double-buffer hazard: phase1(it+2) rewrites this buffer only after
        // barrier(it+1); every wave drains its own DS ops (incl. phase2(it)
        // reads) via lgkmcnt(0) before that barrier. Safe with 1 barrier/tile.

        // ---- phase 2: MFMA GEMM, K = 256 (sin || cos), swapped operands ----
        floatx4 acc[2][2];
        #pragma unroll
        for (int mi = 0; mi < 2; ++mi)
            #pragma unroll
            for (int ni = 0; ni < 2; ++ni)
                acc[mi][ni] = (floatx4){0.f, 0.f, 0.f, 0.f};

        #pragma unroll
        for (int ks = 0; ks < 8; ++ks) {
            const int ak = ks * 32 + quad * 8;
            bf16x8 a[2];
            #pragma unroll
            for (int mi = 0; mi < 2; ++mi)
                a[mi] = *(const bf16x8*)&A[(mi * 16 + l15) * LSTR + ak];
            #pragma unroll
            for (int mi = 0; mi < 2; ++mi)
                #pragma unroll
                for (int ni = 0; ni < 2; ++ni)
                    acc[mi][ni] = __builtin_amdgcn_mfma_f32_16x16x32_bf16(
                        b[ks][ni], a[mi], acc[mi][ni], 0, 0, 0);
        }

        // ---- epilogue: D[ch = quad*4 + r][m = l15]; 4 consecutive channels
        // per lane -> one float4 store per (mi,ni). 16B-aligned (quad*4 floats).
        #pragma unroll
        for (int mi = 0; mi < 2; ++mi) {
            #pragma unroll
            for (int ni = 0; ni < 2; ++ni) {
                float* p = out + (size_t)(m0 + mi * 16 + l15) * C_
                               + n0 + ni * 16 + quad * 4;
                *(floatx4*)p = acc[mi][ni];
            }
        }

        tv[0] = tvn[0];
        tv[1] = tvn[1];
    }
}

extern "C" void kernel_launch(void* const* d_in, const int* in_sizes, int n_in,
                              void* d_out, int out_size, void* d_ws, size_t ws_size,
                              hipStream_t stream) {
    const float* t   = (const float*)d_in[0];
    const float* fq  = (const float*)d_in[1];
    const float* As  = (const float*)d_in[2];
    const float* Ac  = (const float*)d_in[3];
    float* outp      = (float*)d_out;

    const int M = in_sizes[0];               // 262144
    // grid: (M / (MT*TPB)) m-blocks x 2 channel-halves, cblk in bit 0
    hipLaunchKernelGGL(fourier_fused, dim3((M / (MT * TPB)) * 2), dim3(256), 0,
                       stream, t, fq, As, Ac, outp);
}

// Round 5
// 281.323 us; speedup vs baseline: 1.0694x; 1.0694x over previous
//
#include <hip/hip_runtime.h>
#include <stdint.h>

// FourierPeriodNet: out[m][c] = sum_f sin(2pi t[m] f[f]) As[c][f] + cos(...) Ac[c][f]
// M = 262144, F = 128, C = 256.
// Round 8: R3 geometry (MT=64, TPB=8, 256 ch/block, dbuf LDS, lgkm-only
// barrier, 2 blocks/CU) + restructured phase 2:
//   - swapped MFMA operands (harness-proven in R4): D[row=channel][col=m]
//     -> each lane holds 4 consecutive channels -> dwordx4 stores.
//   - mi-striped epilogue: loop mi outer, ks inner, acc[4] only (16 VGPR,
//     was 64); store each stripe's 4 float4 right after its MFMAs. Stores
//     spread across the MFMA phase -> continuous HBM write stream instead of
//     a burst at tile end (write duty was ~50%).
// R4 lesson: do NOT force occupancy via launch_bounds with a 128-reg b hoard.

typedef __bf16 bf16x8 __attribute__((ext_vector_type(8)));
typedef float  floatx4 __attribute__((ext_vector_type(4)));

#define MT    64          // M rows per tile
#define F_    128         // frequencies
#define C_    256         // channels (N)
#define LSTR  264         // LDS row stride in bf16 elems: 256 + 8 pad
#define TPB   8           // tiles per block

// Orders LDS only: drain this wave's DS ops, then raw s_barrier. Global stores
// stay outstanding (write-only output, no in-kernel reader).
#define LDS_BARRIER() asm volatile("s_waitcnt lgkmcnt(0)\n\ts_barrier" ::: "memory")

__global__ __launch_bounds__(256, 2)
void fourier_fused(const float* __restrict__ t,
                   const float* __restrict__ freqs,
                   const float* __restrict__ amp_sin,
                   const float* __restrict__ amp_cos,
                   float* __restrict__ out)
{
    __shared__ __align__(16) __bf16 Af[2][MT * LSTR];   // 2 x 33792 B

    const int tid  = threadIdx.x;
    const int wave = tid >> 6;       // 0..3 -> 64-col slice of C
    const int lane = tid & 63;
    const int l15  = lane & 15;
    const int quad = lane >> 4;      // 0..3
    const int n0   = wave * 64;

    const int fgrp = tid & 15;       // which octet of 8 freqs (phase 1)
    const int rsub = tid >> 4;       // 0..15 (row-within-16 in phase 1)

    const int tile0 = blockIdx.x * TPB;

    // ---- t prefetch for tile 0 (in flight during freq/B setup) ----
    float tv[4];
    #pragma unroll
    for (int p = 0; p < 4; ++p)
        tv[p] = t[tile0 * MT + p * 16 + rsub];

    // ---- freqs for phase 1 ----
    const float4 f0v = *(const float4*)(freqs + fgrp * 8);
    const float4 f1v = *(const float4*)(freqs + fgrp * 8 + 4);
    const float fr[8] = {f0v.x, f0v.y, f0v.z, f0v.w, f1v.x, f1v.y, f1v.z, f1v.w};

    // ---- amp fragments (A-operand of swapped MFMA), held in VGPRs.
    // Lane (quad,l15) holds amp[n0 + ni*16 + l15][(ks&3)*32 + quad*8 + j];
    // ks<4 -> amp_sin (k=0..127), ks>=4 -> amp_cos (k=128..255).
    bf16x8 b[8][4];
    #pragma unroll
    for (int ks = 0; ks < 8; ++ks) {
        const float* __restrict__ amp = (ks < 4) ? amp_sin : amp_cos;
        const int f0 = (ks & 3) * 32 + quad * 8;
        #pragma unroll
        for (int ni = 0; ni < 4; ++ni) {
            const float* p = amp + (n0 + ni * 16 + l15) * F_ + f0;
            const float4 b0 = *(const float4*)(p);
            const float4 b1 = *(const float4*)(p + 4);
            b[ks][ni][0] = (__bf16)b0.x; b[ks][ni][1] = (__bf16)b0.y;
            b[ks][ni][2] = (__bf16)b0.z; b[ks][ni][3] = (__bf16)b0.w;
            b[ks][ni][4] = (__bf16)b1.x; b[ks][ni][5] = (__bf16)b1.y;
            b[ks][ni][6] = (__bf16)b1.z; b[ks][ni][7] = (__bf16)b1.w;
        }
    }

    #pragma unroll 2
    for (int it = 0; it < TPB; ++it) {
        const int m0 = (tile0 + it) * MT;
        __bf16* __restrict__ A = Af[it & 1];

        // ---- prefetch next tile's t (latency hides under trans + MFMA) ----
        float tvn[4];
        {
            const int mb = (it + 1 < TPB) ? (m0 + MT) : tile0 * MT;
            #pragma unroll
            for (int p = 0; p < 4; ++p)
                tvn[p] = t[mb + p * 16 + rsub];
        }

        // ---- phase 1: sin/cos features -> LDS (bf16, [m][k] rows) ----
        #pragma unroll
        for (int pass = 0; pass < 4; ++pass) {
            const int ml = pass * 16 + rsub;
            const float tval = tv[pass];
            bf16x8 sv, cv;
            #pragma unroll
            for (int j = 0; j < 8; ++j) {
                // sin(2*pi*x) = v_sin(fract(x)): HW sin/cos take REVOLUTIONS
                const float r = __builtin_amdgcn_fractf(tval * fr[j]);
                sv[j] = (__bf16)__builtin_amdgcn_sinf(r);
                cv[j] = (__bf16)__builtin_amdgcn_cosf(r);
            }
            *(bf16x8*)&A[ml * LSTR + fgrp * 8]      = sv;   // k = 0..127  : sin
            *(bf16x8*)&A[ml * LSTR + F_ + fgrp * 8] = cv;   // k = 128..255: cos
        }
        LDS_BARRIER();
        // Double-buffer hazard: phase1(it+2) rewrites this buffer only after
        // barrier(it+1); every wave drains its own DS ops (incl. this tile's
        // ds_reads below) via lgkmcnt(0) before that barrier.

        // ---- phase 2: MFMA, K = 256, mi-striped; stores interleaved ----
        #pragma unroll
        for (int mi = 0; mi < 4; ++mi) {
            floatx4 acc[4];
            #pragma unroll
            for (int ni = 0; ni < 4; ++ni)
                acc[ni] = (floatx4){0.f, 0.f, 0.f, 0.f};

            #pragma unroll
            for (int ks = 0; ks < 8; ++ks) {
                const bf16x8 a =
                    *(const bf16x8*)&A[(mi * 16 + l15) * LSTR + ks * 32 + quad * 8];
                #pragma unroll
                for (int ni = 0; ni < 4; ++ni)
                    acc[ni] = __builtin_amdgcn_mfma_f32_16x16x32_bf16(
                        b[ks][ni], a, acc[ni], 0, 0, 0);
            }

            // stripe epilogue: D[ch = ni*16 + quad*4 + r][m = mi*16 + l15];
            // one 16B store per ni (4 consecutive channels per lane).
            #pragma unroll
            for (int ni = 0; ni < 4; ++ni) {
                float* p = out + (size_t)(m0 + mi * 16 + l15) * C_
                               + n0 + ni * 16 + quad * 4;
                *(floatx4*)p = acc[ni];
            }
        }

        #pragma unroll
        for (int p = 0; p < 4; ++p) tv[p] = tvn[p];
    }
}

extern "C" void kernel_launch(void* const* d_in, const int* in_sizes, int n_in,
                              void* d_out, int out_size, void* d_ws, size_t ws_size,
                              hipStream_t stream) {
    const float* t   = (const float*)d_in[0];
    const float* fq  = (const float*)d_in[1];
    const float* As  = (const float*)d_in[2];
    const float* Ac  = (const float*)d_in[3];
    float* outp      = (float*)d_out;

    const int M = in_sizes[0];               // 262144
    hipLaunchKernelGGL(fourier_fused, dim3(M / (MT * TPB)), dim3(256), 0, stream,
                       t, fq, As, Ac, outp);
}

// Round 6
// 279.163 us; speedup vs baseline: 1.0777x; 1.0077x over previous
//
#include <hip/hip_runtime.h>
#include <stdint.h>

// FourierPeriodNet: out[m][c] = sum_f sin(2pi t[m] f[f]) As[c][f] + cos(...) Ac[c][f]
// M = 262144, F = 128, C = 256.
// Round 9: software-pipelined producer/consumer. R5 geometry kept (MT=64,
// TPB=8, 256ch/block, dbuf LDS, lgkm-only barrier, swapped-operand MFMA,
// float4 stores, 2 blocks/CU). Change: each iteration CONSUMES tile it
// (4 mi-stripes: ds_read -> MFMA -> float4 stores) while PRODUCING tile it+1
// (per-stripe trans chunk + ds_write into buf^1). Trans (VALU/trans pipe),
// MFMA (matrix pipe) and stores (VMEM) co-issue within each wave instead of
// being separated into barrier-gated phases -> continuous HBM write stream.
// Barrier count unchanged: one lgkm-only barrier per tile, same dbuf hazard
// argument as R3 (production targets buf^1; next overwrite of buf happens
// one barrier later).

typedef __bf16 bf16x8 __attribute__((ext_vector_type(8)));
typedef float  floatx4 __attribute__((ext_vector_type(4)));

#define MT    64          // M rows per tile
#define F_    128         // frequencies
#define C_    256         // channels (N)
#define LSTR  264         // LDS row stride in bf16 elems: 256 + 8 pad
#define TPB   8           // tiles per block

// Orders LDS only: drain this wave's DS ops, then raw s_barrier. Global stores
// stay outstanding (write-only output, no in-kernel reader).
#define LDS_BARRIER() asm volatile("s_waitcnt lgkmcnt(0)\n\ts_barrier" ::: "memory")

__global__ __launch_bounds__(256, 2)
void fourier_fused(const float* __restrict__ t,
                   const float* __restrict__ freqs,
                   const float* __restrict__ amp_sin,
                   const float* __restrict__ amp_cos,
                   float* __restrict__ out)
{
    __shared__ __align__(16) __bf16 Af[2][MT * LSTR];   // 2 x 33792 B

    const int tid  = threadIdx.x;
    const int wave = tid >> 6;       // 0..3 -> 64-col slice of C
    const int lane = tid & 63;
    const int l15  = lane & 15;
    const int quad = lane >> 4;      // 0..3
    const int n0   = wave * 64;

    const int fgrp = tid & 15;       // which octet of 8 freqs (producer)
    const int rsub = tid >> 4;       // 0..15 (row-within-16, producer)

    const int tile0 = blockIdx.x * TPB;

    // ---- freqs ----
    const float4 f0v = *(const float4*)(freqs + fgrp * 8);
    const float4 f1v = *(const float4*)(freqs + fgrp * 8 + 4);
    const float fr[8] = {f0v.x, f0v.y, f0v.z, f0v.w, f1v.x, f1v.y, f1v.z, f1v.w};

    // ---- amp fragments (A-operand of swapped MFMA), held in VGPRs.
    // Lane (quad,l15) holds amp[n0 + ni*16 + l15][(ks&3)*32 + quad*8 + j];
    // ks<4 -> amp_sin (k=0..127), ks>=4 -> amp_cos (k=128..255).
    bf16x8 b[8][4];
    #pragma unroll
    for (int ks = 0; ks < 8; ++ks) {
        const float* __restrict__ amp = (ks < 4) ? amp_sin : amp_cos;
        const int f0 = (ks & 3) * 32 + quad * 8;
        #pragma unroll
        for (int ni = 0; ni < 4; ++ni) {
            const float* p = amp + (n0 + ni * 16 + l15) * F_ + f0;
            const float4 b0 = *(const float4*)(p);
            const float4 b1 = *(const float4*)(p + 4);
            b[ks][ni][0] = (__bf16)b0.x; b[ks][ni][1] = (__bf16)b0.y;
            b[ks][ni][2] = (__bf16)b0.z; b[ks][ni][3] = (__bf16)b0.w;
            b[ks][ni][4] = (__bf16)b1.x; b[ks][ni][5] = (__bf16)b1.y;
            b[ks][ni][6] = (__bf16)b1.z; b[ks][ni][7] = (__bf16)b1.w;
        }
    }

    // ---- prologue: produce tile0 into Af[0] ----
    float tprod[4];                  // t for the tile currently being produced
    #pragma unroll
    for (int p = 0; p < 4; ++p)
        tprod[p] = t[tile0 * MT + p * 16 + rsub];

    #pragma unroll
    for (int pass = 0; pass < 4; ++pass) {
        const float tval = tprod[pass];
        bf16x8 sv, cv;
        #pragma unroll
        for (int j = 0; j < 8; ++j) {
            // sin(2*pi*x) = v_sin(fract(x)): HW sin/cos take REVOLUTIONS
            const float r = __builtin_amdgcn_fractf(tval * fr[j]);
            sv[j] = (__bf16)__builtin_amdgcn_sinf(r);
            cv[j] = (__bf16)__builtin_amdgcn_cosf(r);
        }
        *(bf16x8*)&Af[0][(pass * 16 + rsub) * LSTR + fgrp * 8]      = sv;
        *(bf16x8*)&Af[0][(pass * 16 + rsub) * LSTR + F_ + fgrp * 8] = cv;
    }

    // t for tile1 (production during it=0)
    #pragma unroll
    for (int p = 0; p < 4; ++p)
        tprod[p] = t[(tile0 + 1) * MT + p * 16 + rsub];

    LDS_BARRIER();

    #pragma unroll 2
    for (int it = 0; it < TPB; ++it) {
        const int m0   = (tile0 + it) * MT;
        const int cur  = it & 1;
        const int nxt  = cur ^ 1;
        const bool prod = (it + 1 < TPB);

        // prefetch t for tile it+2 (consumed as tprod next iteration)
        float tnext[4];
        {
            const int mb = (it + 2 < TPB) ? (m0 + 2 * MT) : tile0 * MT;
            #pragma unroll
            for (int p = 0; p < 4; ++p)
                tnext[p] = t[mb + p * 16 + rsub];
        }

        // ---- 4 stripes: consume(it, mi) interleaved with produce(it+1, mi) ----
        #pragma unroll
        for (int mi = 0; mi < 4; ++mi) {
            // consumer reads issue first (ds_read latency under trans below)
            bf16x8 a[8];
            #pragma unroll
            for (int ks = 0; ks < 8; ++ks)
                a[ks] = *(const bf16x8*)
                    &Af[cur][(mi * 16 + l15) * LSTR + ks * 32 + quad * 8];

            // producer chunk: pass mi of tile it+1 -> Af[nxt]
            if (prod) {
                const float tval = tprod[mi];
                bf16x8 sv, cv;
                #pragma unroll
                for (int j = 0; j < 8; ++j) {
                    const float r = __builtin_amdgcn_fractf(tval * fr[j]);
                    sv[j] = (__bf16)__builtin_amdgcn_sinf(r);
                    cv[j] = (__bf16)__builtin_amdgcn_cosf(r);
                }
                *(bf16x8*)&Af[nxt][(mi * 16 + rsub) * LSTR + fgrp * 8]      = sv;
                *(bf16x8*)&Af[nxt][(mi * 16 + rsub) * LSTR + F_ + fgrp * 8] = cv;
            }

            // MFMA for stripe mi (K = 256), swapped operands
            floatx4 acc[4];
            #pragma unroll
            for (int ni = 0; ni < 4; ++ni)
                acc[ni] = (floatx4){0.f, 0.f, 0.f, 0.f};
            #pragma unroll
            for (int ks = 0; ks < 8; ++ks)
                #pragma unroll
                for (int ni = 0; ni < 4; ++ni)
                    acc[ni] = __builtin_amdgcn_mfma_f32_16x16x32_bf16(
                        b[ks][ni], a[ks], acc[ni], 0, 0, 0);

            // stripe epilogue: D[ch = ni*16 + quad*4 + r][m = mi*16 + l15];
            // one 16B store per ni (4 consecutive channels per lane).
            #pragma unroll
            for (int ni = 0; ni < 4; ++ni) {
                float* p = out + (size_t)(m0 + mi * 16 + l15) * C_
                               + n0 + ni * 16 + quad * 4;
                *(floatx4*)p = acc[ni];
            }
        }

        LDS_BARRIER();
        // Hazard: iteration it+1's producer writes Af[cur] — first possible
        // write is after this barrier; every wave drained its Af[cur] reads
        // (lgkmcnt(0)) before it. Producer writes to Af[nxt] this iteration
        // are likewise drained before iteration it+1's consumers read them.

        #pragma unroll
        for (int p = 0; p < 4; ++p) tprod[p] = tnext[p];
    }
}

extern "C" void kernel_launch(void* const* d_in, const int* in_sizes, int n_in,
                              void* d_out, int out_size, void* d_ws, size_t ws_size,
                              hipStream_t stream) {
    const float* t   = (const float*)d_in[0];
    const float* fq  = (const float*)d_in[1];
    const float* As  = (const float*)d_in[2];
    const float* Ac  = (const float*)d_in[3];
    float* outp      = (float*)d_out;

    const int M = in_sizes[0];               // 262144
    hipLaunchKernelGGL(fourier_fused, dim3(M / (MT * TPB)), dim3(256), 0, stream,
                       t, fq, As, Ac, outp);
}